// Round 7
// baseline (439.988 us; speedup 1.0000x reference)
//
#include <hip/hip_runtime.h>

#define Bc 2
#define Sc 2048
#define Dc 2048
#define Hc 16
#define DHc 128

typedef _Float16 f16;
typedef __attribute__((ext_vector_type(4))) _Float16 v4h;
typedef __attribute__((ext_vector_type(8))) _Float16 v8h;
typedef __attribute__((ext_vector_type(4))) float v4f;
typedef __attribute__((ext_vector_type(16))) float v16f;
typedef __attribute__((ext_vector_type(4))) float f32x4;

// ---------------------------------------------------------------------------
// Convert f32 inputs -> f16 once.
// ---------------------------------------------------------------------------
__global__ void cvt_kernel(const float* __restrict__ x, const float* __restrict__ wq,
                           const float* __restrict__ wk, const float* __restrict__ wv,
                           f16* __restrict__ xh, f16* __restrict__ wqh,
                           f16* __restrict__ wkh, f16* __restrict__ wvh)
{
    int bid = blockIdx.x;
    const float* src; f16* dst; int idx;
    if (bid < 8192)       { src = x;  dst = xh;  idx = bid; }
    else if (bid < 12288) { src = wq; dst = wqh; idx = bid - 8192; }
    else if (bid < 16384) { src = wk; dst = wkh; idx = bid - 12288; }
    else                  { src = wv; dst = wvh; idx = bid - 16384; }
    int i = idx * 256 + threadIdx.x;
    f32x4 v = ((const f32x4*)src)[i];
    v4h hv; hv[0]=(f16)v[0]; hv[1]=(f16)v[1]; hv[2]=(f16)v[2]; hv[3]=(f16)v[3];
    ((v4h*)dst)[i] = hv;
}

// ---------------------------------------------------------------------------
// Fused QKV projection GEMM C[4096][6144] = X . [wq;wk;wv]^T.
// 128x256 tile, BK=64, 8 waves, 768 blocks (3 exact rounds).
// Round 7: A-OPERAND FROM GLOBAL->REGISTERS (LDS was the bottleneck:
// r3/r5/r6 all pinned at ~35% MfmaUtil; reads 128K + writes 48K per K-tile
// @ ~85 B/cyc = 2100 cyc > MFMA 1242). A-frags are row-contiguous in xh and
// L1-resident (16 KiB/K-tile, reused by 4 waves) -> load them straight to
// VGPRs (8 x dwordx4 per wave per K-tile, double-set, prefetch 1 tile ahead).
// LDS now carries B only: reads 64K + writes 32K ~= 1150 cyc < MFMA 1242
// -> MFMA-bound. 3-slot B ring (96 KiB), ONE s_barrier + ONE vmcnt(12)
// per K-tile (own-wave wait BEFORE the barrier => publication sound;
// vmcnt retires in issue order, 12 = this iter's B-stage(4)+A-loads(8)).
// ---------------------------------------------------------------------------
__launch_bounds__(512, 2)
__global__ void proj256_kernel(const f16* __restrict__ xh, const f16* __restrict__ wall,
                               const float* __restrict__ cs, const float* __restrict__ sn,
                               f16* __restrict__ qh, f16* __restrict__ kh,
                               f16* __restrict__ vt)
{
    const int bid = blockIdx.x;
    const int swz = (bid & 7) * 96 + (bid >> 3);     // 768 % 8 == 0 -> bijective
    const int mt = swz & 31, nt = swz >> 5;
    const int m0 = mt * 128, n0 = nt * 256;

    const int tid = threadIdx.x;
    const int wid = tid >> 6, lane = tid & 63;
    const int wr = wid >> 2, wc = wid & 3;           // 2 x 4 waves
    const int l15 = lane & 15, quad = lane >> 4;
    const int x7 = l15 & 7;

    // LDS: 3 B-slots x 256x64 halves = 98304 B
    __shared__ __align__(16) f16 lds[49152];

    // B staging sources (swizzle-inverse permuted global columns)
    const f16* bS[4];
    #pragma unroll
    for (int j = 0; j < 4; ++j) {
        int c = tid + j * 512;
        int r = c >> 3, s = c & 7;
        bS[j] = wall + (size_t)(n0 + r) * Dc + ((s ^ (r & 7)) * 8);
    }

    // A-fragment global base pointers (per mi), row-contiguous
    const f16* aP[4];
    #pragma unroll
    for (int mi = 0; mi < 4; ++mi)
        aP[mi] = xh + (size_t)(m0 + wr * 64 + mi * 16 + l15) * Dc + quad * 8;

#define GLD(src_, dst_)                                                         \
    __builtin_amdgcn_global_load_lds(                                           \
        (const __attribute__((address_space(1))) void*)(src_),                  \
        (__attribute__((address_space(3))) void*)(dst_), 16, 0, 0)

#define STAGE_B(kt_, slot_) do {                                                \
        const int _ko = (kt_) * 64;                                             \
        f16* _b = lds + (slot_) * 16384;                                        \
        GLD(bS[0] + _ko, _b + wid * 512);                                       \
        GLD(bS[1] + _ko, _b + 4096  + wid * 512);                               \
        GLD(bS[2] + _ko, _b + 8192  + wid * 512);                               \
        GLD(bS[3] + _ko, _b + 12288 + wid * 512);                               \
    } while (0)

#define LOAD_A(set_, kt_) do {                                                  \
        const int _ko = (kt_) * 64;                                             \
        _Pragma("unroll")                                                       \
        for (int mi = 0; mi < 4; ++mi) {                                        \
            set_[0][mi] = *(const v8h*)(aP[mi] + _ko);                          \
            set_[1][mi] = *(const v8h*)(aP[mi] + _ko + 32);                     \
        }                                                                       \
    } while (0)

#define RDB(bf_, slot_) do {                                                    \
        const f16* _Bb = lds + (slot_) * 16384;                                 \
        _Pragma("unroll")                                                       \
        for (int kk = 0; kk < 2; ++kk)                                          \
            _Pragma("unroll")                                                   \
            for (int ni = 0; ni < 4; ++ni)                                      \
                bf_[kk][ni] = *(const v8h*)(_Bb + (wc * 64 + ni * 16 + l15) * 64 \
                                            + (((kk * 4 + quad) ^ x7) * 8));    \
    } while (0)

#define MM(a_, bf_) do {                                                        \
        __builtin_amdgcn_s_setprio(1);                                          \
        _Pragma("unroll")                                                       \
        for (int kk = 0; kk < 2; ++kk)                                          \
            _Pragma("unroll")                                                   \
            for (int mi = 0; mi < 4; ++mi)                                      \
                _Pragma("unroll")                                               \
                for (int ni = 0; ni < 4; ++ni)                                  \
                    acc[mi][ni] = __builtin_amdgcn_mfma_f32_16x16x32_f16(       \
                        a_[kk][mi], bf_[kk][ni], acc[mi][ni], 0, 0, 0);         \
        __builtin_amdgcn_s_setprio(0);                                          \
    } while (0)

#define VMW12 asm volatile("s_waitcnt vmcnt(12)" ::: "memory")
#define BARM  asm volatile("s_barrier" ::: "memory")

    v4f acc[4][4];
    #pragma unroll
    for (int i = 0; i < 4; ++i)
        #pragma unroll
        for (int j = 0; j < 4; ++j)
            acc[i][j] = (v4f){0.f, 0.f, 0.f, 0.f};

    v8h a0[2][4], a1[2][4];

    // prologue: stage B(0),B(1); load A(0); publish B(0)
    STAGE_B(0, 0);
    STAGE_B(1, 1);
    LOAD_A(a0, 0);
    VMW12;                       // own B(0) contribution landed (12 newer)
    BARM;                        // all waves' B(0) published

    int bR = 0, bSt = 2;

    #pragma unroll 1
    for (int tt = 0; tt < 32; tt += 2) {
        // t = tt (even): compute on a0, prefetch A(t+1) into a1
        if (tt + 2 < 32) STAGE_B(tt + 2, bSt);
        LOAD_A(a1, tt + 1);                       // tt+1 <= 31 always
        {
            v8h bf[2][4];
            RDB(bf, bR);
            MM(a0, bf);
        }
        VMW12;                   // own B(t+1) contribution landed
        BARM;                    // publish B(t+1); slot bSt' WAR-safe
        bR = (bR == 2) ? 0 : bR + 1;
        bSt = (bSt == 2) ? 0 : bSt + 1;

        // t = tt+1 (odd): compute on a1, prefetch A(t+2) into a0
        if (tt + 3 < 32) STAGE_B(tt + 3, bSt);
        if (tt + 2 < 32) LOAD_A(a0, tt + 2);
        {
            v8h bf[2][4];
            RDB(bf, bR);
            MM(a1, bf);
        }
        VMW12;
        BARM;
        bR = (bR == 2) ? 0 : bR + 1;
        bSt = (bSt == 2) ? 0 : bSt + 1;
    }
    __syncthreads();             // full drain before LDS reuse in epilogue

#undef STAGE_B
#undef LOAD_A
#undef GLD
#undef RDB
#undef MM
#undef VMW12
#undef BARM

    // ---------------- epilogue (z uniform per block: BN=256 | 2048) ---------
    const int z = n0 >> 11;
    const int bb = m0 >> 11, s0 = m0 & 2047;

    if (z < 2) {
        f16 (*Ep)[264] = (f16(*)[264])lds;      // 128 x 264 x 2B = 67.5 KiB < 96
        #pragma unroll
        for (int mi = 0; mi < 4; ++mi)
            #pragma unroll
            for (int ni = 0; ni < 4; ++ni)
                #pragma unroll
                for (int r = 0; r < 4; ++r)
                    Ep[wr * 64 + mi * 16 + quad * 4 + r][wc * 64 + ni * 16 + l15] =
                        (f16)acc[mi][ni][r];
        __syncthreads();
        f16* outp = (z == 0) ? qh : kh;
        const float scl = (z == 0) ? 0.08838834764831845f : 1.0f;
        #pragma unroll
        for (int it = 0; it < 8; ++it) {
            int ch = tid + it * 512, row = ch >> 5, c = ch & 31;
            v8h val = *(const v8h*)&Ep[row][c * 8];
            int s = s0 + row;
            int nn = (n0 & 2047) + c * 8;
            int h = nn >> 7, d0 = nn & 127;
            const float* cp = cs + (size_t)s * DHc + d0;
            const float* sp = sn + (size_t)s * DHc + d0;
            f32x4 ca = *(const f32x4*)cp, cb = *(const f32x4*)(cp + 4);
            f32x4 sa = *(const f32x4*)sp, sb = *(const f32x4*)(sp + 4);
            float v[8];
            #pragma unroll
            for (int j = 0; j < 8; ++j) v[j] = (float)val[j];
            v8h rv;
            rv[0] = (f16)((v[0]*ca[0] - v[1]*sa[0]) * scl);
            rv[1] = (f16)((v[1]*ca[1] + v[0]*sa[1]) * scl);
            rv[2] = (f16)((v[2]*ca[2] - v[3]*sa[2]) * scl);
            rv[3] = (f16)((v[3]*ca[3] + v[2]*sa[3]) * scl);
            rv[4] = (f16)((v[4]*cb[0] - v[5]*sb[0]) * scl);
            rv[5] = (f16)((v[5]*cb[1] + v[4]*sb[1]) * scl);
            rv[6] = (f16)((v[6]*cb[2] - v[7]*sb[2]) * scl);
            rv[7] = (f16)((v[7]*cb[3] + v[6]*sb[3]) * scl);
            *(v8h*)(outp + ((size_t)(bb * Hc + h) * Sc + s) * DHc + d0) = rv;
        }
    } else {
        f16 (*Ep)[136] = (f16(*)[136])lds;      // 256 x 136 x 2B = 69.6 KiB < 96
        #pragma unroll
        for (int mi = 0; mi < 4; ++mi)
            #pragma unroll
            for (int ni = 0; ni < 4; ++ni)
                #pragma unroll
                for (int r = 0; r < 4; ++r)
                    Ep[wc * 64 + ni * 16 + l15][wr * 64 + mi * 16 + quad * 4 + r] =
                        (f16)acc[mi][ni][r];
        __syncthreads();
        #pragma unroll
        for (int it = 0; it < 8; ++it) {
            int ch = tid + it * 512, n = ch >> 4, cm = ch & 15;
            int nn = (n0 & 2047) + n;
            int h = nn >> 7, d = nn & 127;
            int s = s0 + cm * 8;
            *(v8h*)(vt + ((size_t)(bb * Hc + h) * DHc + d) * Sc + s) =
                *(const v8h*)&Ep[n][cm * 8];
        }
    }
}

// ---------------------------------------------------------------------------
// Fallback proj (ws too small) + separate rope.
// ---------------------------------------------------------------------------
__launch_bounds__(256)
__global__ void proj_kernel(const float* __restrict__ x, const float* __restrict__ wq,
                            const float* __restrict__ wk, const float* __restrict__ wv,
                            f16* __restrict__ qh, f16* __restrict__ kh, f16* __restrict__ vt)
{
    const int z = blockIdx.z;
    const float* w = (z == 0) ? wq : ((z == 1) ? wk : wv);
    const int m0 = blockIdx.x * 128, n0 = blockIdx.y * 128;
    const int tid = threadIdx.x, lane = tid & 63, wid = tid >> 6;
    const int wm = wid >> 1, wn = wid & 1;
    const int l15 = lane & 15, quad = lane >> 4;

    __shared__ __align__(16) f16 smem[2 * 128 * 72];
    f16 (*As)[72] = (f16(*)[72])smem;
    f16 (*Bs)[72] = (f16(*)[72])(smem + 128 * 72);

    v4f acc[4][4];
    for (int i = 0; i < 4; ++i)
        for (int j = 0; j < 4; ++j)
            acc[i][j] = (v4f){0.f, 0.f, 0.f, 0.f};

    for (int k0 = 0; k0 < Dc; k0 += 64) {
        __syncthreads();
        for (int it = 0; it < 4; ++it) {
            int chunk = tid + it * 256;
            int r = chunk >> 3, cc = chunk & 7;
            const f32x4* pa = (const f32x4*)(x + (size_t)(m0 + r) * Dc + k0 + cc * 8);
            f32x4 a0 = pa[0], a1 = pa[1];
            v8h ha;
            ha[0]=(f16)a0[0]; ha[1]=(f16)a0[1]; ha[2]=(f16)a0[2]; ha[3]=(f16)a0[3];
            ha[4]=(f16)a1[0]; ha[5]=(f16)a1[1]; ha[6]=(f16)a1[2]; ha[7]=(f16)a1[3];
            *(v8h*)&As[r][cc * 8] = ha;
            const f32x4* pb = (const f32x4*)(w + (size_t)(n0 + r) * Dc + k0 + cc * 8);
            f32x4 b0 = pb[0], b1 = pb[1];
            v8h hb;
            hb[0]=(f16)b0[0]; hb[1]=(f16)b0[1]; hb[2]=(f16)b0[2]; hb[3]=(f16)b0[3];
            hb[4]=(f16)b1[0]; hb[5]=(f16)b1[1]; hb[6]=(f16)b1[2]; hb[7]=(f16)b1[3];
            *(v8h*)&Bs[r][cc * 8] = hb;
        }
        __syncthreads();
        for (int kk = 0; kk < 2; ++kk) {
            v8h af[4], bf[4];
            for (int mi = 0; mi < 4; ++mi)
                af[mi] = *(const v8h*)&As[wm * 64 + mi * 16 + l15][kk * 32 + quad * 8];
            for (int ni = 0; ni < 4; ++ni)
                bf[ni] = *(const v8h*)&Bs[wn * 64 + ni * 16 + l15][kk * 32 + quad * 8];
            for (int mi = 0; mi < 4; ++mi)
                for (int ni = 0; ni < 4; ++ni)
                    acc[mi][ni] = __builtin_amdgcn_mfma_f32_16x16x32_f16(
                        af[mi], bf[ni], acc[mi][ni], 0, 0, 0);
        }
    }
    __syncthreads();
    f16 (*Ep)[136] = (f16(*)[136])smem;
    for (int mi = 0; mi < 4; ++mi)
        for (int ni = 0; ni < 4; ++ni)
            for (int r = 0; r < 4; ++r) {
                int ml = wm * 64 + mi * 16 + quad * 4 + r;
                int nl = wn * 64 + ni * 16 + l15;
                f16 val = (f16)acc[mi][ni][r];
                if (z == 2) Ep[nl][ml] = val;
                else        Ep[ml][nl] = val;
            }
    __syncthreads();
    const int b = m0 >> 11, s0 = m0 & 2047, h = n0 >> 7;
    if (z < 2) {
        f16* outp = (z == 0) ? qh : kh;
        for (int it = 0; it < 8; ++it) {
            int ch = tid + it * 256, row = ch >> 4, c = ch & 15;
            *(v8h*)(outp + ((size_t)((b * Hc + h) * Sc) + s0 + row) * DHc + c * 8) =
                *(const v8h*)&Ep[row][c * 8];
        }
    } else {
        for (int it = 0; it < 8; ++it) {
            int ch = tid + it * 256, row = ch >> 4, c = ch & 15;
            *(v8h*)(vt + ((size_t)((b * Hc + h) * DHc) + row) * Sc + s0 + c * 8) =
                *(const v8h*)&Ep[row][c * 8];
        }
    }
}

__global__ void rope_kernel(f16* __restrict__ qh, f16* __restrict__ kh,
                            const float* __restrict__ cs, const float* __restrict__ sn)
{
    int i  = blockIdx.x * 256 + threadIdx.x;
    int d2 = i & 63;
    int s  = (i >> 6) & (Sc - 1);
    int bh = i >> 17;
    f16* t = blockIdx.y ? kh : qh;
    float scale = blockIdx.y ? 1.0f : 0.08838834764831845f;
    float c  = cs[s * DHc + 2 * d2];
    float sv = sn[s * DHc + 2 * d2];
    f16* p = t + ((size_t)bh * Sc + s) * DHc + 2 * d2;
    float t0 = (float)p[0], t1 = (float)p[1];
    p[0] = (f16)((t0 * c - t1 * sv) * scale);
    p[1] = (f16)((t1 * c + t0 * sv) * scale);
}

// ---------------------------------------------------------------------------
// Flash attention v6: balanced + XCD-local (unchanged).
// ---------------------------------------------------------------------------
__launch_bounds__(256, 2)
__global__ void attn_kernel(const f16* __restrict__ qh, const f16* __restrict__ kh,
                            const f16* __restrict__ vt, float* __restrict__ out)
{
    const int L = blockIdx.x;
    const int slot = L >> 3;
    const int bh = (L & 7) * 4 + (slot >> 3);
    const int p  = slot & 7;
    const int b = bh >> 4, h = bh & 15;
    const int tid = threadIdx.x, lane = tid & 63, w = tid >> 6;
    const int l31 = lane & 31, half = lane >> 5;
    const int sw = l31 & 7;

    __shared__ __align__(16) f16 smem[32768];     // K dbuf 32KB + V dbuf 32KB
    f16* ksm = smem;
    f16* vsm = smem + 16384;

    const size_t bhoff = (size_t)bh * Sc * DHc;

    const f16* ksrc[4]; const f16* vsrc[4];
    f16* kdst[4]; f16* vdst[4];
    #pragma unroll
    for (int j = 0; j < 4; ++j) {
        int slot0 = j * 256 + w * 64;
        {   int r = (slot0 >> 4) + (lane >> 4);
            int c = (lane & 15) ^ (r & 7);
            ksrc[j] = kh + bhoff + (size_t)r * DHc + c * 8;
            kdst[j] = ksm + slot0 * 8; }
        {   int r = (slot0 >> 3) + (lane >> 3);
            int c = (lane & 7) ^ (r & 7);
            vsrc[j] = vt + bhoff + (size_t)r * Sc + c * 8;
            vdst[j] = vsm + slot0 * 8; }
    }

#define STAGE(kt_, buf_) do {                                                   \
        int _ko = (kt_) * 64 * DHc;                                             \
        int _vo = (kt_) * 64;                                                   \
        int _lb = (buf_) * 8192;                                                \
        _Pragma("unroll")                                                       \
        for (int j = 0; j < 4; ++j) {                                           \
            __builtin_amdgcn_global_load_lds(                                   \
                (const __attribute__((address_space(1))) void*)(ksrc[j] + _ko), \
                (__attribute__((address_space(3))) void*)(kdst[j] + _lb), 16, 0, 0); \
            __builtin_amdgcn_global_load_lds(                                   \
                (const __attribute__((address_space(1))) void*)(vsrc[j] + _vo), \
                (__attribute__((address_space(3))) void*)(vdst[j] + _lb), 16, 0, 0); \
        } } while (0)

    const int qtA = 15 - p;
    const int nktA = 2 * qtA + 2;     // + nktB = 34 for every block

    int ibuf = 0;
    STAGE(0, 0);

    #pragma unroll 1
    for (int ph = 0; ph < 2; ++ph) {
        const int qt  = ph ? p : qtA;
        const int nkt = 2 * qt + 2;
        const int q0  = qt * 128 + w * 32;
        const int qg  = q0 + l31;

        v8h qf[8];
        const f16* qrow = qh + bhoff + (size_t)qg * DHc;
        #pragma unroll
        for (int s = 0; s < 8; ++s)
            qf[s] = *(const v8h*)(qrow + s * 16 + half * 8);

        float l_run = 0.f;
        v16f o[4];
        #pragma unroll
        for (int i = 0; i < 4; ++i)
            #pragma unroll
            for (int r = 0; r < 16; ++r) o[i][r] = 0.f;

        #pragma unroll 1
        for (int kt = 0; kt < nkt; ++kt, ++ibuf) {
            __syncthreads();             // publishes buf[ibuf&1]
            const int buf = ibuf & 1;
            const int ni = ibuf + 1;
            if (ni < 34) {
                int tn = (ni < nktA) ? ni : ni - nktA;
                STAGE(tn, ni & 1);
            }
            if (q0 + 31 < kt * 64) continue;   // fully masked; barriers uniform

            const f16* kbuf = ksm + buf * 8192;
            const f16* vbuf = vsm + buf * 8192;
            const bool do1 = (kt * 64 + 32 <= q0 + 31);

            v16f st0, st1;
            #pragma unroll
            for (int r = 0; r < 16; ++r) { st0[r] = 0.f; st1[r] = 0.f; }
            #pragma unroll
            for (int s = 0; s < 8; ++s) {
                int c = ((s * 2 + half) ^ sw) * 8;
                v8h kf0 = *(const v8h*)(kbuf + l31 * 128 + c);
                st0 = __builtin_amdgcn_mfma_f32_32x32x16_f16(kf0, qf[s], st0, 0, 0, 0);
                if (do1) {
                    v8h kf1 = *(const v8h*)(kbuf + (32 + l31) * 128 + c);
                    st1 = __builtin_amdgcn_mfma_f32_32x32x16_f16(kf1, qf[s], st1, 0, 0, 0);
                }
            }

            float sum = 0.f;
            #pragma unroll
            for (int r = 0; r < 16; ++r) {
                int key = kt * 64 + (r & 3) + 8 * (r >> 2) + 4 * half;
                float sv = (key > qg) ? -1e30f : st0[r];
                float pe = __expf(sv);
                st0[r] = pe; sum += pe;
            }
            if (do1) {
                #pragma unroll
                for (int r = 0; r < 16; ++r) {
                    int key = kt * 64 + 32 + (r & 3) + 8 * (r >> 2) + 4 * half;
                    float sv = (key > qg) ? -1e30f : st1[r];
                    float pe = __expf(sv);
                    st1[r] = pe; sum += pe;
                }
            }
            sum += __shfl_xor(sum, 32);
            l_run += sum;

            #pragma unroll
            for (int s2 = 0; s2 < 4; ++s2) {
                v4h bfr;
                bfr[0]=(f16)st0[4*s2]; bfr[1]=(f16)st0[4*s2+1];
                bfr[2]=(f16)st0[4*s2+2]; bfr[3]=(f16)st0[4*s2+3];
                int c = ((s2 ^ sw) * 8) + half * 4;
                #pragma unroll
                for (int dt = 0; dt < 4; ++dt) {
                    v4h vf = *(const v4h*)(vbuf + (dt * 32 + l31) * 64 + c);
                    o[dt] = __builtin_amdgcn_mfma_f32_32x32x8f16(vf, bfr, o[dt], 0, 0, 0);
                }
            }
            if (do1) {
                #pragma unroll
                for (int s2 = 0; s2 < 4; ++s2) {
                    v4h bfr;
                    bfr[0]=(f16)st1[4*s2]; bfr[1]=(f16)st1[4*s2+1];
                    bfr[2]=(f16)st1[4*s2+2]; bfr[3]=(f16)st1[4*s2+3];
                    int c = (((4 + s2) ^ sw) * 8) + half * 4;
                    #pragma unroll
                    for (int dt = 0; dt < 4; ++dt) {
                        v4h vf = *(const v4h*)(vbuf + (dt * 32 + l31) * 64 + c);
                        o[dt] = __builtin_amdgcn_mfma_f32_32x32x8f16(vf, bfr, o[dt], 0, 0, 0);
                    }
                }
            }
        }

        float inv = 1.f / l_run;
        float mxd = -1e30f;
        #pragma unroll
        for (int dt = 0; dt < 4; ++dt)
            #pragma unroll
            for (int r = 0; r < 16; ++r) {
                o[dt][r] *= inv;
                mxd = fmaxf(mxd, o[dt][r]);
            }
        mxd = fmaxf(mxd, __shfl_xor(mxd, 32));
        float sd = 0.f;
        #pragma unroll
        for (int dt = 0; dt < 4; ++dt)
            #pragma unroll
            for (int r = 0; r < 16; ++r) {
                float t = __expf(o[dt][r] - mxd);
                o[dt][r] = t;
                sd += t;
            }
        sd += __shfl_xor(sd, 32);
        float rinv = 1.f / sd;

        float* orow = out + (size_t)(b * Sc + qg) * Dc + h * DHc;
        #pragma unroll
        for (int dt = 0; dt < 4; ++dt)
            #pragma unroll
            for (int g = 0; g < 4; ++g) {
                f32x4 vv;
                vv[0] = o[dt][4*g+0] * rinv;
                vv[1] = o[dt][4*g+1] * rinv;
                vv[2] = o[dt][4*g+2] * rinv;
                vv[3] = o[dt][4*g+3] * rinv;
                *(f32x4*)(orow + dt * 32 + g * 8 + half * 4) = vv;
            }
    }
#undef STAGE
}

extern "C" void kernel_launch(void* const* d_in, const int* in_sizes, int n_in,
                              void* d_out, int out_size, void* d_ws, size_t ws_size,
                              hipStream_t stream)
{
    const float* x  = (const float*)d_in[0];
    const float* wq = (const float*)d_in[1];
    const float* wk = (const float*)d_in[2];
    const float* wv = (const float*)d_in[3];
    const float* cs = (const float*)d_in[4];
    const float* sn = (const float*)d_in[5];
    float* out = (float*)d_out;

    const size_t tsz = (size_t)Bc * Hc * Sc * DHc;   // 8,388,608 halves
    f16* qh = (f16*)d_ws;
    f16* kh = qh + tsz;
    f16* vt = kh + tsz;

    if (ws_size >= 11 * tsz) {
        f16* xh  = vt + tsz;
        f16* wqh = xh + tsz;
        f16* wkh = wqh + tsz / 2;
        f16* wvh = wkh + tsz / 2;
        cvt_kernel<<<20480, 256, 0, stream>>>(x, wq, wk, wv, xh, wqh, wkh, wvh);
        // wqh/wkh/wvh are contiguous -> one stacked-W GEMM, N = 6144
        proj256_kernel<<<768, 512, 0, stream>>>(xh, wqh, cs, sn, qh, kh, vt);
    } else {
        proj_kernel<<<dim3(32, 16, 3), 256, 0, stream>>>(x, wq, wk, wv, qh, kh, vt);
        rope_kernel<<<dim3(16384, 2), 256, 0, stream>>>(qh, kh, cs, sn);
    }
    attn_kernel<<<256, 256, 0, stream>>>(qh, kh, vt, out);
}

// Round 8
// 306.746 us; speedup vs baseline: 1.4344x; 1.4344x over previous
//
#include <hip/hip_runtime.h>

#define Bc 2
#define Sc 2048
#define Dc 2048
#define Hc 16
#define DHc 128

typedef _Float16 f16;
typedef __attribute__((ext_vector_type(4))) _Float16 v4h;
typedef __attribute__((ext_vector_type(8))) _Float16 v8h;
typedef __attribute__((ext_vector_type(4))) float v4f;
typedef __attribute__((ext_vector_type(16))) float v16f;
typedef __attribute__((ext_vector_type(4))) float f32x4;

// ---------------------------------------------------------------------------
// Convert f32 inputs -> f16 once.
// ---------------------------------------------------------------------------
__global__ void cvt_kernel(const float* __restrict__ x, const float* __restrict__ wq,
                           const float* __restrict__ wk, const float* __restrict__ wv,
                           f16* __restrict__ xh, f16* __restrict__ wqh,
                           f16* __restrict__ wkh, f16* __restrict__ wvh)
{
    int bid = blockIdx.x;
    const float* src; f16* dst; int idx;
    if (bid < 8192)       { src = x;  dst = xh;  idx = bid; }
    else if (bid < 12288) { src = wq; dst = wqh; idx = bid - 8192; }
    else if (bid < 16384) { src = wk; dst = wkh; idx = bid - 12288; }
    else                  { src = wv; dst = wvh; idx = bid - 16384; }
    int i = idx * 256 + threadIdx.x;
    f32x4 v = ((const f32x4*)src)[i];
    v4h hv; hv[0]=(f16)v[0]; hv[1]=(f16)v[1]; hv[2]=(f16)v[2]; hv[3]=(f16)v[3];
    ((v4h*)dst)[i] = hv;
}

// ---------------------------------------------------------------------------
// Fused QKV projection GEMM C[4096][6144] = X . [wq;wk;wv]^T.
// 128x256 tile, BK=64, 8 waves, 768 blocks (3 exact rounds), T2 swizzle.
// REVERTED to the r5 structure (best measured 124.9 us): 2 phases per K-tile,
// 3-buffer LDS ring, counted vmcnt(6). (r7's A-from-global regressed 2x:
// per-lane 4KB-strided loads -> 16-line scatter per instr, VMEM-latency-bound.)
// ---------------------------------------------------------------------------
__launch_bounds__(512, 2)
__global__ void proj256_kernel(const f16* __restrict__ xh, const f16* __restrict__ wall,
                               const float* __restrict__ cs, const float* __restrict__ sn,
                               f16* __restrict__ qh, f16* __restrict__ kh,
                               f16* __restrict__ vt)
{
    const int bid = blockIdx.x;
    const int swz = (bid & 7) * 96 + (bid >> 3);     // 768 % 8 == 0 -> bijective
    const int mt = swz & 31, nt = swz >> 5;
    const int m0 = mt * 128, n0 = nt * 256;

    const int tid = threadIdx.x;
    const int wid = tid >> 6, lane = tid & 63;
    const int wr = wid >> 2, wc = wid & 3;           // 2 x 4 waves
    const int l15 = lane & 15, quad = lane >> 4;
    const int x7 = l15 & 7;

    // LDS: 3 buffers x (A 128x64 + B 256x64) halves = 147456 B
    __shared__ __align__(16) f16 lds[73728];

    const f16* aS[2]; const f16* bS[4];
    #pragma unroll
    for (int j = 0; j < 2; ++j) {
        int c = tid + j * 512;
        int r = c >> 3, s = c & 7;
        aS[j] = xh + (size_t)(m0 + r) * Dc + ((s ^ (r & 7)) * 8);
    }
    #pragma unroll
    for (int j = 0; j < 4; ++j) {
        int c = tid + j * 512;
        int r = c >> 3, s = c & 7;
        bS[j] = wall + (size_t)(n0 + r) * Dc + ((s ^ (r & 7)) * 8);
    }

#define GLD(src_, dst_)                                                         \
    __builtin_amdgcn_global_load_lds(                                           \
        (const __attribute__((address_space(1))) void*)(src_),                  \
        (__attribute__((address_space(3))) void*)(dst_), 16, 0, 0)

#define STAGE_P0(kt_, buf_) do {                                                \
        const int _ko = (kt_) * 64;                                             \
        f16* _b = lds + (buf_) * 24576;                                         \
        GLD(aS[0] + _ko, _b + wid * 512);                                       \
        GLD(aS[1] + _ko, _b + 4096 + wid * 512);                                \
        GLD(bS[0] + _ko, _b + 8192 + wid * 512);                                \
    } while (0)

#define STAGE_P1(kt_, buf_) do {                                                \
        const int _ko = (kt_) * 64;                                             \
        f16* _b = lds + (buf_) * 24576;                                         \
        GLD(bS[1] + _ko, _b + 8192 + 4096  + wid * 512);                        \
        GLD(bS[2] + _ko, _b + 8192 + 8192  + wid * 512);                        \
        GLD(bS[3] + _ko, _b + 8192 + 12288 + wid * 512);                        \
    } while (0)

#define VMW6  asm volatile("s_waitcnt vmcnt(6)"  ::: "memory")
#define VMW0  asm volatile("s_waitcnt vmcnt(0)"  ::: "memory")
#define LGKM0 asm volatile("s_waitcnt lgkmcnt(0)" ::: "memory")
#define BAR   __builtin_amdgcn_s_barrier()

#define PHASE(kk_, bR_) do {                                                    \
        const f16* _Ab = lds + (bR_) * 24576;                                   \
        const f16* _Bb = _Ab + 8192;                                            \
        v8h af[4], bf[4];                                                       \
        _Pragma("unroll")                                                       \
        for (int mi = 0; mi < 4; ++mi)                                          \
            af[mi] = *(const v8h*)(_Ab + (wr * 64 + mi * 16 + l15) * 64         \
                                   + ((((kk_) * 4 + quad) ^ x7) * 8));          \
        _Pragma("unroll")                                                       \
        for (int ni = 0; ni < 4; ++ni)                                          \
            bf[ni] = *(const v8h*)(_Bb + (wc * 64 + ni * 16 + l15) * 64         \
                                   + ((((kk_) * 4 + quad) ^ x7) * 8));          \
        PH_TAIL;                                                                \
        __builtin_amdgcn_s_setprio(1);                                          \
        _Pragma("unroll")                                                       \
        for (int mi = 0; mi < 4; ++mi)                                          \
            _Pragma("unroll")                                                   \
            for (int ni = 0; ni < 4; ++ni)                                      \
                acc[mi][ni] = __builtin_amdgcn_mfma_f32_16x16x32_f16(           \
                    af[mi], bf[ni], acc[mi][ni], 0, 0, 0);                      \
        __builtin_amdgcn_s_setprio(0);                                          \
    } while (0)

    v4f acc[4][4];
    #pragma unroll
    for (int i = 0; i < 4; ++i)
        #pragma unroll
        for (int j = 0; j < 4; ++j)
            acc[i][j] = (v4f){0.f, 0.f, 0.f, 0.f};

    // prologue: tiles 0,1 fully staged; wait tile 0 (all but newest 6)
    STAGE_P0(0, 0); STAGE_P1(0, 0);
    STAGE_P0(1, 1); STAGE_P1(1, 1);
    VMW6;
    BAR;

    int bR = 0;      // buffer holding tile t
    int bSt = 2;     // buffer receiving tile t+2

    #pragma unroll 1
    for (int t = 0; t < 32; ++t) {
        // ---- phase 0: frags kk=0 + 3 staged loads ----
        {
#define PH_TAIL do { if (t + 2 < 32) STAGE_P0(t + 2, bSt); BAR; } while (0)
            PHASE(0, bR);
#undef PH_TAIL
        }
        BAR;
        // ---- phase 1: frags kk=1 + 3 staged loads + counted wait ----
        {
#define PH_TAIL do { if (t + 2 < 32) STAGE_P1(t + 2, bSt);                      \
                     if (t < 30) { VMW6; } else { VMW0; }                       \
                     BAR; } while (0)
            PHASE(1, bR);
#undef PH_TAIL
        }
        LGKM0;
        BAR;             // all reads of bR retired; next iter may overwrite it

        bR  = (bR  == 2) ? 0 : bR  + 1;
        bSt = (bSt == 2) ? 0 : bSt + 1;
    }

#undef STAGE_P0
#undef STAGE_P1
#undef GLD
#undef VMW6
#undef VMW0
#undef LGKM0
#undef BAR
#undef PHASE

    // ---------------- epilogue (z uniform per block: BN=256 | 2048) ---------
    const int z = n0 >> 11;
    const int bb = m0 >> 11, s0 = m0 & 2047;

    if (z < 2) {
        f16 (*Ep)[264] = (f16(*)[264])lds;
        #pragma unroll
        for (int mi = 0; mi < 4; ++mi)
            #pragma unroll
            for (int ni = 0; ni < 4; ++ni)
                #pragma unroll
                for (int r = 0; r < 4; ++r)
                    Ep[wr * 64 + mi * 16 + quad * 4 + r][wc * 64 + ni * 16 + l15] =
                        (f16)acc[mi][ni][r];
        __syncthreads();
        f16* outp = (z == 0) ? qh : kh;
        const float scl = (z == 0) ? 0.08838834764831845f : 1.0f;
        #pragma unroll
        for (int it = 0; it < 8; ++it) {
            int ch = tid + it * 512, row = ch >> 5, c = ch & 31;
            v8h val = *(const v8h*)&Ep[row][c * 8];
            int s = s0 + row;
            int nn = (n0 & 2047) + c * 8;
            int h = nn >> 7, d0 = nn & 127;
            const float* cp = cs + (size_t)s * DHc + d0;
            const float* sp = sn + (size_t)s * DHc + d0;
            f32x4 ca = *(const f32x4*)cp, cb = *(const f32x4*)(cp + 4);
            f32x4 sa = *(const f32x4*)sp, sb = *(const f32x4*)(sp + 4);
            float v[8];
            #pragma unroll
            for (int j = 0; j < 8; ++j) v[j] = (float)val[j];
            v8h rv;
            rv[0] = (f16)((v[0]*ca[0] - v[1]*sa[0]) * scl);
            rv[1] = (f16)((v[1]*ca[1] + v[0]*sa[1]) * scl);
            rv[2] = (f16)((v[2]*ca[2] - v[3]*sa[2]) * scl);
            rv[3] = (f16)((v[3]*ca[3] + v[2]*sa[3]) * scl);
            rv[4] = (f16)((v[4]*cb[0] - v[5]*sb[0]) * scl);
            rv[5] = (f16)((v[5]*cb[1] + v[4]*sb[1]) * scl);
            rv[6] = (f16)((v[6]*cb[2] - v[7]*sb[2]) * scl);
            rv[7] = (f16)((v[7]*cb[3] + v[6]*sb[3]) * scl);
            *(v8h*)(outp + ((size_t)(bb * Hc + h) * Sc + s) * DHc + d0) = rv;
        }
    } else {
        f16 (*Ep)[136] = (f16(*)[136])lds;
        #pragma unroll
        for (int mi = 0; mi < 4; ++mi)
            #pragma unroll
            for (int ni = 0; ni < 4; ++ni)
                #pragma unroll
                for (int r = 0; r < 4; ++r)
                    Ep[wc * 64 + ni * 16 + l15][wr * 64 + mi * 16 + quad * 4 + r] =
                        (f16)acc[mi][ni][r];
        __syncthreads();
        #pragma unroll
        for (int it = 0; it < 8; ++it) {
            int ch = tid + it * 512, n = ch >> 4, cm = ch & 15;
            int nn = (n0 & 2047) + n;
            int h = nn >> 7, d = nn & 127;
            int s = s0 + cm * 8;
            *(v8h*)(vt + ((size_t)(bb * Hc + h) * DHc + d) * Sc + s) =
                *(const v8h*)&Ep[n][cm * 8];
        }
    }
}

// ---------------------------------------------------------------------------
// Fallback proj (ws too small) + separate rope.
// ---------------------------------------------------------------------------
__launch_bounds__(256)
__global__ void proj_kernel(const float* __restrict__ x, const float* __restrict__ wq,
                            const float* __restrict__ wk, const float* __restrict__ wv,
                            f16* __restrict__ qh, f16* __restrict__ kh, f16* __restrict__ vt)
{
    const int z = blockIdx.z;
    const float* w = (z == 0) ? wq : ((z == 1) ? wk : wv);
    const int m0 = blockIdx.x * 128, n0 = blockIdx.y * 128;
    const int tid = threadIdx.x, lane = tid & 63, wid = tid >> 6;
    const int wm = wid >> 1, wn = wid & 1;
    const int l15 = lane & 15, quad = lane >> 4;

    __shared__ __align__(16) f16 smem[2 * 128 * 72];
    f16 (*As)[72] = (f16(*)[72])smem;
    f16 (*Bs)[72] = (f16(*)[72])(smem + 128 * 72);

    v4f acc[4][4];
    for (int i = 0; i < 4; ++i)
        for (int j = 0; j < 4; ++j)
            acc[i][j] = (v4f){0.f, 0.f, 0.f, 0.f};

    for (int k0 = 0; k0 < Dc; k0 += 64) {
        __syncthreads();
        for (int it = 0; it < 4; ++it) {
            int chunk = tid + it * 256;
            int r = chunk >> 3, cc = chunk & 7;
            const f32x4* pa = (const f32x4*)(x + (size_t)(m0 + r) * Dc + k0 + cc * 8);
            f32x4 a0 = pa[0], a1 = pa[1];
            v8h ha;
            ha[0]=(f16)a0[0]; ha[1]=(f16)a0[1]; ha[2]=(f16)a0[2]; ha[3]=(f16)a0[3];
            ha[4]=(f16)a1[0]; ha[5]=(f16)a1[1]; ha[6]=(f16)a1[2]; ha[7]=(f16)a1[3];
            *(v8h*)&As[r][cc * 8] = ha;
            const f32x4* pb = (const f32x4*)(w + (size_t)(n0 + r) * Dc + k0 + cc * 8);
            f32x4 b0 = pb[0], b1 = pb[1];
            v8h hb;
            hb[0]=(f16)b0[0]; hb[1]=(f16)b0[1]; hb[2]=(f16)b0[2]; hb[3]=(f16)b0[3];
            hb[4]=(f16)b1[0]; hb[5]=(f16)b1[1]; hb[6]=(f16)b1[2]; hb[7]=(f16)b1[3];
            *(v8h*)&Bs[r][cc * 8] = hb;
        }
        __syncthreads();
        for (int kk = 0; kk < 2; ++kk) {
            v8h af[4], bf[4];
            for (int mi = 0; mi < 4; ++mi)
                af[mi] = *(const v8h*)&As[wm * 64 + mi * 16 + l15][kk * 32 + quad * 8];
            for (int ni = 0; ni < 4; ++ni)
                bf[ni] = *(const v8h*)&Bs[wn * 64 + ni * 16 + l15][kk * 32 + quad * 8];
            for (int mi = 0; mi < 4; ++mi)
                for (int ni = 0; ni < 4; ++ni)
                    acc[mi][ni] = __builtin_amdgcn_mfma_f32_16x16x32_f16(
                        af[mi], bf[ni], acc[mi][ni], 0, 0, 0);
        }
    }
    __syncthreads();
    f16 (*Ep)[136] = (f16(*)[136])smem;
    for (int mi = 0; mi < 4; ++mi)
        for (int ni = 0; ni < 4; ++ni)
            for (int r = 0; r < 4; ++r) {
                int ml = wm * 64 + mi * 16 + quad * 4 + r;
                int nl = wn * 64 + ni * 16 + l15;
                f16 val = (f16)acc[mi][ni][r];
                if (z == 2) Ep[nl][ml] = val;
                else        Ep[ml][nl] = val;
            }
    __syncthreads();
    const int b = m0 >> 11, s0 = m0 & 2047, h = n0 >> 7;
    if (z < 2) {
        f16* outp = (z == 0) ? qh : kh;
        for (int it = 0; it < 8; ++it) {
            int ch = tid + it * 256, row = ch >> 4, c = ch & 15;
            *(v8h*)(outp + ((size_t)((b * Hc + h) * Sc) + s0 + row) * DHc + c * 8) =
                *(const v8h*)&Ep[row][c * 8];
        }
    } else {
        for (int it = 0; it < 8; ++it) {
            int ch = tid + it * 256, row = ch >> 4, c = ch & 15;
            *(v8h*)(vt + ((size_t)((b * Hc + h) * DHc) + row) * Sc + s0 + c * 8) =
                *(const v8h*)&Ep[row][c * 8];
        }
    }
}

__global__ void rope_kernel(f16* __restrict__ qh, f16* __restrict__ kh,
                            const float* __restrict__ cs, const float* __restrict__ sn)
{
    int i  = blockIdx.x * 256 + threadIdx.x;
    int d2 = i & 63;
    int s  = (i >> 6) & (Sc - 1);
    int bh = i >> 17;
    f16* t = blockIdx.y ? kh : qh;
    float scale = blockIdx.y ? 1.0f : 0.08838834764831845f;
    float c  = cs[s * DHc + 2 * d2];
    float sv = sn[s * DHc + 2 * d2];
    f16* p = t + ((size_t)bh * Sc + s) * DHc + 2 * d2;
    float t0 = (float)p[0], t1 = (float)p[1];
    p[0] = (f16)((t0 * c - t1 * sv) * scale);
    p[1] = (f16)((t1 * c + t0 * sv) * scale);
}

// ---------------------------------------------------------------------------
// Flash attention v8: 8-wave blocks. 256 blocks (1/CU, XCD-local bh as v6),
// 512 threads: waves 0-3 process q-tile (15-p), waves 4-7 process q-tile p
// CONCURRENTLY -> 2 waves/SIMD of independent work (latency hiding; v6 was
// 1 wave/SIMD, measured ~11.8k cyc/KV-iter vs ~2.6k throughput estimate).
// K/V staged ONCE per kt (v6 staged everything twice across its 2 phases).
// Loop length 2(15-p)+2 <= 32 < v6's 34. Per-wave body/softmax/epilogue
// unchanged; staging partition re-derived for 8 waves (j<2).
// ---------------------------------------------------------------------------
__launch_bounds__(512, 2)
__global__ void attn_kernel(const f16* __restrict__ qh, const f16* __restrict__ kh,
                            const f16* __restrict__ vt, float* __restrict__ out)
{
    const int L = blockIdx.x;
    const int slot = L >> 3;
    const int bh = (L & 7) * 4 + (slot >> 3);
    const int p  = slot & 7;
    const int b = bh >> 4, h = bh & 15;
    const int tid = threadIdx.x, lane = tid & 63, w = tid >> 6;
    const int g = w >> 2, wg = w & 3;            // group (which q-tile), wave-in-group
    const int l31 = lane & 31, half = lane >> 5;
    const int sw = l31 & 7;

    __shared__ __align__(16) f16 smem[32768];     // K dbuf 32KB + V dbuf 32KB
    f16* ksm = smem;
    f16* vsm = smem + 16384;

    const size_t bhoff = (size_t)bh * Sc * DHc;

    // staging bases: 8 waves, j<2 (swizzled global source, lane-linear LDS dst)
    const f16* ksrc[2]; const f16* vsrc[2];
    f16* kdst[2]; f16* vdst[2];
    #pragma unroll
    for (int j = 0; j < 2; ++j) {
        int slot0 = j * 512 + w * 64;
        {   int r = (slot0 >> 4) + (lane >> 4);
            int c = (lane & 15) ^ (r & 7);
            ksrc[j] = kh + bhoff + (size_t)r * DHc + c * 8;
            kdst[j] = ksm + slot0 * 8; }
        {   int r = (slot0 >> 3) + (lane >> 3);
            int c = (lane & 7) ^ (r & 7);
            vsrc[j] = vt + bhoff + (size_t)r * Sc + c * 8;
            vdst[j] = vsm + slot0 * 8; }
    }

#define STAGE(kt_, buf_) do {                                                   \
        int _ko = (kt_) * 64 * DHc;                                             \
        int _vo = (kt_) * 64;                                                   \
        int _lb = (buf_) * 8192;                                                \
        _Pragma("unroll")                                                       \
        for (int j = 0; j < 2; ++j) {                                           \
            __builtin_amdgcn_global_load_lds(                                   \
                (const __attribute__((address_space(1))) void*)(ksrc[j] + _ko), \
                (__attribute__((address_space(3))) void*)(kdst[j] + _lb), 16, 0, 0); \
            __builtin_amdgcn_global_load_lds(                                   \
                (const __attribute__((address_space(1))) void*)(vsrc[j] + _vo), \
                (__attribute__((address_space(3))) void*)(vdst[j] + _lb), 16, 0, 0); \
        } } while (0)

    const int qt  = g ? p : 15 - p;              // per-wave q-tile
    const int nkt = 2 * (15 - p) + 2;            // block loop = larger tile's range
    const int q0  = qt * 128 + wg * 32;
    const int qg  = q0 + l31;

    v8h qf[8];
    const f16* qrow = qh + bhoff + (size_t)qg * DHc;
    #pragma unroll
    for (int s = 0; s < 8; ++s)
        qf[s] = *(const v8h*)(qrow + s * 16 + half * 8);

    float l_run = 0.f;
    v16f o[4];
    #pragma unroll
    for (int i = 0; i < 4; ++i)
        #pragma unroll
        for (int r = 0; r < 16; ++r) o[i][r] = 0.f;

    STAGE(0, 0);

    #pragma unroll 1
    for (int kt = 0; kt < nkt; ++kt) {
        __syncthreads();             // publishes buf[kt&1]; uniform (nkt is block-uniform)
        if (kt + 1 < nkt) STAGE(kt + 1, (kt + 1) & 1);
        if (q0 + 31 < kt * 64) continue;   // fully masked (incl. group-1 tail); barriers uniform

        const f16* kbuf = ksm + (kt & 1) * 8192;
        const f16* vbuf = vsm + (kt & 1) * 8192;
        const bool do1 = (kt * 64 + 32 <= q0 + 31);

        v16f st0, st1;
        #pragma unroll
        for (int r = 0; r < 16; ++r) { st0[r] = 0.f; st1[r] = 0.f; }
        #pragma unroll
        for (int s = 0; s < 8; ++s) {
            int c = ((s * 2 + half) ^ sw) * 8;
            v8h kf0 = *(const v8h*)(kbuf + l31 * 128 + c);
            st0 = __builtin_amdgcn_mfma_f32_32x32x16_f16(kf0, qf[s], st0, 0, 0, 0);
            if (do1) {
                v8h kf1 = *(const v8h*)(kbuf + (32 + l31) * 128 + c);
                st1 = __builtin_amdgcn_mfma_f32_32x32x16_f16(kf1, qf[s], st1, 0, 0, 0);
            }
        }

        float sum = 0.f;
        #pragma unroll
        for (int r = 0; r < 16; ++r) {
            int key = kt * 64 + (r & 3) + 8 * (r >> 2) + 4 * half;
            float sv = (key > qg) ? -1e30f : st0[r];
            float pe = __expf(sv);
            st0[r] = pe; sum += pe;
        }
        if (do1) {
            #pragma unroll
            for (int r = 0; r < 16; ++r) {
                int key = kt * 64 + 32 + (r & 3) + 8 * (r >> 2) + 4 * half;
                float sv = (key > qg) ? -1e30f : st1[r];
                float pe = __expf(sv);
                st1[r] = pe; sum += pe;
            }
        }
        sum += __shfl_xor(sum, 32);
        l_run += sum;

        // O^T += V^T . P^T (P^T straight from registers)
        #pragma unroll
        for (int s2 = 0; s2 < 4; ++s2) {
            v4h bfr;
            bfr[0]=(f16)st0[4*s2]; bfr[1]=(f16)st0[4*s2+1];
            bfr[2]=(f16)st0[4*s2+2]; bfr[3]=(f16)st0[4*s2+3];
            int c = ((s2 ^ sw) * 8) + half * 4;
            #pragma unroll
            for (int dt = 0; dt < 4; ++dt) {
                v4h vf = *(const v4h*)(vbuf + (dt * 32 + l31) * 64 + c);
                o[dt] = __builtin_amdgcn_mfma_f32_32x32x8f16(vf, bfr, o[dt], 0, 0, 0);
            }
        }
        if (do1) {
            #pragma unroll
            for (int s2 = 0; s2 < 4; ++s2) {
                v4h bfr;
                bfr[0]=(f16)st1[4*s2]; bfr[1]=(f16)st1[4*s2+1];
                bfr[2]=(f16)st1[4*s2+2]; bfr[3]=(f16)st1[4*s2+3];
                int c = (((4 + s2) ^ sw) * 8) + half * 4;
                #pragma unroll
                for (int dt = 0; dt < 4; ++dt) {
                    v4h vf = *(const v4h*)(vbuf + (dt * 32 + l31) * 64 + c);
                    o[dt] = __builtin_amdgcn_mfma_f32_32x32x8f16(vf, bfr, o[dt], 0, 0, 0);
                }
            }
        }
    }

    // epilogue: normalize + softmax over Dh + paired-lane stores
    float inv = 1.f / l_run;
    float mxd = -1e30f;
    #pragma unroll
    for (int dt = 0; dt < 4; ++dt)
        #pragma unroll
        for (int r = 0; r < 16; ++r) {
            o[dt][r] *= inv;
            mxd = fmaxf(mxd, o[dt][r]);
        }
    mxd = fmaxf(mxd, __shfl_xor(mxd, 32));
    float sd = 0.f;
    #pragma unroll
    for (int dt = 0; dt < 4; ++dt)
        #pragma unroll
        for (int r = 0; r < 16; ++r) {
            float t = __expf(o[dt][r] - mxd);
            o[dt][r] = t;
            sd += t;
        }
    sd += __shfl_xor(sd, 32);
    float rinv = 1.f / sd;

    float* orow = out + (size_t)(b * Sc + qg) * Dc + h * DHc;
    #pragma unroll
    for (int dt = 0; dt < 4; ++dt)
        #pragma unroll
        for (int g2 = 0; g2 < 4; ++g2) {
            f32x4 vv;
            vv[0] = o[dt][4*g2+0] * rinv;
            vv[1] = o[dt][4*g2+1] * rinv;
            vv[2] = o[dt][4*g2+2] * rinv;
            vv[3] = o[dt][4*g2+3] * rinv;
            *(f32x4*)(orow + dt * 32 + g2 * 8 + half * 4) = vv;
        }
#undef STAGE
}

extern "C" void kernel_launch(void* const* d_in, const int* in_sizes, int n_in,
                              void* d_out, int out_size, void* d_ws, size_t ws_size,
                              hipStream_t stream)
{
    const float* x  = (const float*)d_in[0];
    const float* wq = (const float*)d_in[1];
    const float* wk = (const float*)d_in[2];
    const float* wv = (const float*)d_in[3];
    const float* cs = (const float*)d_in[4];
    const float* sn = (const float*)d_in[5];
    float* out = (float*)d_out;

    const size_t tsz = (size_t)Bc * Hc * Sc * DHc;   // 8,388,608 halves
    f16* qh = (f16*)d_ws;
    f16* kh = qh + tsz;
    f16* vt = kh + tsz;

    if (ws_size >= 11 * tsz) {
        f16* xh  = vt + tsz;
        f16* wqh = xh + tsz;
        f16* wkh = wqh + tsz / 2;
        f16* wvh = wkh + tsz / 2;
        cvt_kernel<<<20480, 256, 0, stream>>>(x, wq, wk, wv, xh, wqh, wkh, wvh);
        // wqh/wkh/wvh are contiguous -> one stacked-W GEMM, N = 6144
        proj256_kernel<<<768, 512, 0, stream>>>(xh, wqh, cs, sn, qh, kh, vt);
    } else {
        proj_kernel<<<dim3(32, 16, 3), 256, 0, stream>>>(x, wq, wk, wv, qh, kh, vt);
        rope_kernel<<<dim3(16384, 2), 256, 0, stream>>>(qh, kh, cs, sn);
    }
    attn_kernel<<<256, 512, 0, stream>>>(qh, kh, vt, out);
}

// Round 9
// 297.458 us; speedup vs baseline: 1.4792x; 1.0312x over previous
//
#include <hip/hip_runtime.h>

#define Bc 2
#define Sc 2048
#define Dc 2048
#define Hc 16
#define DHc 128

typedef _Float16 f16;
typedef __attribute__((ext_vector_type(4))) _Float16 v4h;
typedef __attribute__((ext_vector_type(8))) _Float16 v8h;
typedef __attribute__((ext_vector_type(4))) float v4f;
typedef __attribute__((ext_vector_type(16))) float v16f;
typedef __attribute__((ext_vector_type(4))) float f32x4;

// ---------------------------------------------------------------------------
// Convert f32 inputs -> f16 once.
// ---------------------------------------------------------------------------
__global__ void cvt_kernel(const float* __restrict__ x, const float* __restrict__ wq,
                           const float* __restrict__ wk, const float* __restrict__ wv,
                           f16* __restrict__ xh, f16* __restrict__ wqh,
                           f16* __restrict__ wkh, f16* __restrict__ wvh)
{
    int bid = blockIdx.x;
    const float* src; f16* dst; int idx;
    if (bid < 8192)       { src = x;  dst = xh;  idx = bid; }
    else if (bid < 12288) { src = wq; dst = wqh; idx = bid - 8192; }
    else if (bid < 16384) { src = wk; dst = wkh; idx = bid - 12288; }
    else                  { src = wv; dst = wvh; idx = bid - 16384; }
    int i = idx * 256 + threadIdx.x;
    f32x4 v = ((const f32x4*)src)[i];
    v4h hv; hv[0]=(f16)v[0]; hv[1]=(f16)v[1]; hv[2]=(f16)v[2]; hv[3]=(f16)v[3];
    ((v4h*)dst)[i] = hv;
}

// ---------------------------------------------------------------------------
// Fused QKV projection GEMM C[4096][6144] = X . [wq;wk;wv]^T.
// 128x256 tile, BK=64, 8 waves, 768 blocks (3 exact rounds), T2 swizzle.
// r5 structure (best measured 124.9 us): 2 phases per K-tile, 3-buffer LDS
// ring, counted vmcnt(6). Unchanged this round.
// ---------------------------------------------------------------------------
__launch_bounds__(512, 2)
__global__ void proj256_kernel(const f16* __restrict__ xh, const f16* __restrict__ wall,
                               const float* __restrict__ cs, const float* __restrict__ sn,
                               f16* __restrict__ qh, f16* __restrict__ kh,
                               f16* __restrict__ vt)
{
    const int bid = blockIdx.x;
    const int swz = (bid & 7) * 96 + (bid >> 3);     // 768 % 8 == 0 -> bijective
    const int mt = swz & 31, nt = swz >> 5;
    const int m0 = mt * 128, n0 = nt * 256;

    const int tid = threadIdx.x;
    const int wid = tid >> 6, lane = tid & 63;
    const int wr = wid >> 2, wc = wid & 3;           // 2 x 4 waves
    const int l15 = lane & 15, quad = lane >> 4;
    const int x7 = l15 & 7;

    __shared__ __align__(16) f16 lds[73728];

    const f16* aS[2]; const f16* bS[4];
    #pragma unroll
    for (int j = 0; j < 2; ++j) {
        int c = tid + j * 512;
        int r = c >> 3, s = c & 7;
        aS[j] = xh + (size_t)(m0 + r) * Dc + ((s ^ (r & 7)) * 8);
    }
    #pragma unroll
    for (int j = 0; j < 4; ++j) {
        int c = tid + j * 512;
        int r = c >> 3, s = c & 7;
        bS[j] = wall + (size_t)(n0 + r) * Dc + ((s ^ (r & 7)) * 8);
    }

#define GLD(src_, dst_)                                                         \
    __builtin_amdgcn_global_load_lds(                                           \
        (const __attribute__((address_space(1))) void*)(src_),                  \
        (__attribute__((address_space(3))) void*)(dst_), 16, 0, 0)

#define STAGE_P0(kt_, buf_) do {                                                \
        const int _ko = (kt_) * 64;                                             \
        f16* _b = lds + (buf_) * 24576;                                         \
        GLD(aS[0] + _ko, _b + wid * 512);                                       \
        GLD(aS[1] + _ko, _b + 4096 + wid * 512);                                \
        GLD(bS[0] + _ko, _b + 8192 + wid * 512);                                \
    } while (0)

#define STAGE_P1(kt_, buf_) do {                                                \
        const int _ko = (kt_) * 64;                                             \
        f16* _b = lds + (buf_) * 24576;                                         \
        GLD(bS[1] + _ko, _b + 8192 + 4096  + wid * 512);                        \
        GLD(bS[2] + _ko, _b + 8192 + 8192  + wid * 512);                        \
        GLD(bS[3] + _ko, _b + 8192 + 12288 + wid * 512);                        \
    } while (0)

#define VMW6  asm volatile("s_waitcnt vmcnt(6)"  ::: "memory")
#define VMW0  asm volatile("s_waitcnt vmcnt(0)"  ::: "memory")
#define LGKM0 asm volatile("s_waitcnt lgkmcnt(0)" ::: "memory")
#define BAR   __builtin_amdgcn_s_barrier()

#define PHASE(kk_, bR_) do {                                                    \
        const f16* _Ab = lds + (bR_) * 24576;                                   \
        const f16* _Bb = _Ab + 8192;                                            \
        v8h af[4], bf[4];                                                       \
        _Pragma("unroll")                                                       \
        for (int mi = 0; mi < 4; ++mi)                                          \
            af[mi] = *(const v8h*)(_Ab + (wr * 64 + mi * 16 + l15) * 64         \
                                   + ((((kk_) * 4 + quad) ^ x7) * 8));          \
        _Pragma("unroll")                                                       \
        for (int ni = 0; ni < 4; ++ni)                                          \
            bf[ni] = *(const v8h*)(_Bb + (wc * 64 + ni * 16 + l15) * 64         \
                                   + ((((kk_) * 4 + quad) ^ x7) * 8));          \
        PH_TAIL;                                                                \
        __builtin_amdgcn_s_setprio(1);                                          \
        _Pragma("unroll")                                                       \
        for (int mi = 0; mi < 4; ++mi)                                          \
            _Pragma("unroll")                                                   \
            for (int ni = 0; ni < 4; ++ni)                                      \
                acc[mi][ni] = __builtin_amdgcn_mfma_f32_16x16x32_f16(           \
                    af[mi], bf[ni], acc[mi][ni], 0, 0, 0);                      \
        __builtin_amdgcn_s_setprio(0);                                          \
    } while (0)

    v4f acc[4][4];
    #pragma unroll
    for (int i = 0; i < 4; ++i)
        #pragma unroll
        for (int j = 0; j < 4; ++j)
            acc[i][j] = (v4f){0.f, 0.f, 0.f, 0.f};

    STAGE_P0(0, 0); STAGE_P1(0, 0);
    STAGE_P0(1, 1); STAGE_P1(1, 1);
    VMW6;
    BAR;

    int bR = 0;
    int bSt = 2;

    #pragma unroll 1
    for (int t = 0; t < 32; ++t) {
        {
#define PH_TAIL do { if (t + 2 < 32) STAGE_P0(t + 2, bSt); BAR; } while (0)
            PHASE(0, bR);
#undef PH_TAIL
        }
        BAR;
        {
#define PH_TAIL do { if (t + 2 < 32) STAGE_P1(t + 2, bSt);                      \
                     if (t < 30) { VMW6; } else { VMW0; }                       \
                     BAR; } while (0)
            PHASE(1, bR);
#undef PH_TAIL
        }
        LGKM0;
        BAR;

        bR  = (bR  == 2) ? 0 : bR  + 1;
        bSt = (bSt == 2) ? 0 : bSt + 1;
    }

#undef STAGE_P0
#undef STAGE_P1
#undef GLD
#undef VMW6
#undef VMW0
#undef LGKM0
#undef BAR
#undef PHASE

    const int z = n0 >> 11;
    const int bb = m0 >> 11, s0 = m0 & 2047;

    if (z < 2) {
        f16 (*Ep)[264] = (f16(*)[264])lds;
        #pragma unroll
        for (int mi = 0; mi < 4; ++mi)
            #pragma unroll
            for (int ni = 0; ni < 4; ++ni)
                #pragma unroll
                for (int r = 0; r < 4; ++r)
                    Ep[wr * 64 + mi * 16 + quad * 4 + r][wc * 64 + ni * 16 + l15] =
                        (f16)acc[mi][ni][r];
        __syncthreads();
        f16* outp = (z == 0) ? qh : kh;
        const float scl = (z == 0) ? 0.08838834764831845f : 1.0f;
        #pragma unroll
        for (int it = 0; it < 8; ++it) {
            int ch = tid + it * 512, row = ch >> 5, c = ch & 31;
            v8h val = *(const v8h*)&Ep[row][c * 8];
            int s = s0 + row;
            int nn = (n0 & 2047) + c * 8;
            int h = nn >> 7, d0 = nn & 127;
            const float* cp = cs + (size_t)s * DHc + d0;
            const float* sp = sn + (size_t)s * DHc + d0;
            f32x4 ca = *(const f32x4*)cp, cb = *(const f32x4*)(cp + 4);
            f32x4 sa = *(const f32x4*)sp, sb = *(const f32x4*)(sp + 4);
            float v[8];
            #pragma unroll
            for (int j = 0; j < 8; ++j) v[j] = (float)val[j];
            v8h rv;
            rv[0] = (f16)((v[0]*ca[0] - v[1]*sa[0]) * scl);
            rv[1] = (f16)((v[1]*ca[1] + v[0]*sa[1]) * scl);
            rv[2] = (f16)((v[2]*ca[2] - v[3]*sa[2]) * scl);
            rv[3] = (f16)((v[3]*ca[3] + v[2]*sa[3]) * scl);
            rv[4] = (f16)((v[4]*cb[0] - v[5]*sb[0]) * scl);
            rv[5] = (f16)((v[5]*cb[1] + v[4]*sb[1]) * scl);
            rv[6] = (f16)((v[6]*cb[2] - v[7]*sb[2]) * scl);
            rv[7] = (f16)((v[7]*cb[3] + v[6]*sb[3]) * scl);
            *(v8h*)(outp + ((size_t)(bb * Hc + h) * Sc + s) * DHc + d0) = rv;
        }
    } else {
        f16 (*Ep)[136] = (f16(*)[136])lds;
        #pragma unroll
        for (int mi = 0; mi < 4; ++mi)
            #pragma unroll
            for (int ni = 0; ni < 4; ++ni)
                #pragma unroll
                for (int r = 0; r < 4; ++r)
                    Ep[wc * 64 + ni * 16 + l15][wr * 64 + mi * 16 + quad * 4 + r] =
                        (f16)acc[mi][ni][r];
        __syncthreads();
        #pragma unroll
        for (int it = 0; it < 8; ++it) {
            int ch = tid + it * 512, n = ch >> 4, cm = ch & 15;
            int nn = (n0 & 2047) + n;
            int h = nn >> 7, d = nn & 127;
            int s = s0 + cm * 8;
            *(v8h*)(vt + ((size_t)(bb * Hc + h) * DHc + d) * Sc + s) =
                *(const v8h*)&Ep[n][cm * 8];
        }
    }
}

// ---------------------------------------------------------------------------
// Fallback proj (ws too small) + separate rope.
// ---------------------------------------------------------------------------
__launch_bounds__(256)
__global__ void proj_kernel(const float* __restrict__ x, const float* __restrict__ wq,
                            const float* __restrict__ wk, const float* __restrict__ wv,
                            f16* __restrict__ qh, f16* __restrict__ kh, f16* __restrict__ vt)
{
    const int z = blockIdx.z;
    const float* w = (z == 0) ? wq : ((z == 1) ? wk : wv);
    const int m0 = blockIdx.x * 128, n0 = blockIdx.y * 128;
    const int tid = threadIdx.x, lane = tid & 63, wid = tid >> 6;
    const int wm = wid >> 1, wn = wid & 1;
    const int l15 = lane & 15, quad = lane >> 4;

    __shared__ __align__(16) f16 smem[2 * 128 * 72];
    f16 (*As)[72] = (f16(*)[72])smem;
    f16 (*Bs)[72] = (f16(*)[72])(smem + 128 * 72);

    v4f acc[4][4];
    for (int i = 0; i < 4; ++i)
        for (int j = 0; j < 4; ++j)
            acc[i][j] = (v4f){0.f, 0.f, 0.f, 0.f};

    for (int k0 = 0; k0 < Dc; k0 += 64) {
        __syncthreads();
        for (int it = 0; it < 4; ++it) {
            int chunk = tid + it * 256;
            int r = chunk >> 3, cc = chunk & 7;
            const f32x4* pa = (const f32x4*)(x + (size_t)(m0 + r) * Dc + k0 + cc * 8);
            f32x4 a0 = pa[0], a1 = pa[1];
            v8h ha;
            ha[0]=(f16)a0[0]; ha[1]=(f16)a0[1]; ha[2]=(f16)a0[2]; ha[3]=(f16)a0[3];
            ha[4]=(f16)a1[0]; ha[5]=(f16)a1[1]; ha[6]=(f16)a1[2]; ha[7]=(f16)a1[3];
            *(v8h*)&As[r][cc * 8] = ha;
            const f32x4* pb = (const f32x4*)(w + (size_t)(n0 + r) * Dc + k0 + cc * 8);
            f32x4 b0 = pb[0], b1 = pb[1];
            v8h hb;
            hb[0]=(f16)b0[0]; hb[1]=(f16)b0[1]; hb[2]=(f16)b0[2]; hb[3]=(f16)b0[3];
            hb[4]=(f16)b1[0]; hb[5]=(f16)b1[1]; hb[6]=(f16)b1[2]; hb[7]=(f16)b1[3];
            *(v8h*)&Bs[r][cc * 8] = hb;
        }
        __syncthreads();
        for (int kk = 0; kk < 2; ++kk) {
            v8h af[4], bf[4];
            for (int mi = 0; mi < 4; ++mi)
                af[mi] = *(const v8h*)&As[wm * 64 + mi * 16 + l15][kk * 32 + quad * 8];
            for (int ni = 0; ni < 4; ++ni)
                bf[ni] = *(const v8h*)&Bs[wn * 64 + ni * 16 + l15][kk * 32 + quad * 8];
            for (int mi = 0; mi < 4; ++mi)
                for (int ni = 0; ni < 4; ++ni)
                    acc[mi][ni] = __builtin_amdgcn_mfma_f32_16x16x32_f16(
                        af[mi], bf[ni], acc[mi][ni], 0, 0, 0);
        }
    }
    __syncthreads();
    f16 (*Ep)[136] = (f16(*)[136])smem;
    for (int mi = 0; mi < 4; ++mi)
        for (int ni = 0; ni < 4; ++ni)
            for (int r = 0; r < 4; ++r) {
                int ml = wm * 64 + mi * 16 + quad * 4 + r;
                int nl = wn * 64 + ni * 16 + l15;
                f16 val = (f16)acc[mi][ni][r];
                if (z == 2) Ep[nl][ml] = val;
                else        Ep[ml][nl] = val;
            }
    __syncthreads();
    const int b = m0 >> 11, s0 = m0 & 2047, h = n0 >> 7;
    if (z < 2) {
        f16* outp = (z == 0) ? qh : kh;
        for (int it = 0; it < 8; ++it) {
            int ch = tid + it * 256, row = ch >> 4, c = ch & 15;
            *(v8h*)(outp + ((size_t)((b * Hc + h) * Sc) + s0 + row) * DHc + c * 8) =
                *(const v8h*)&Ep[row][c * 8];
        }
    } else {
        for (int it = 0; it < 8; ++it) {
            int ch = tid + it * 256, row = ch >> 4, c = ch & 15;
            *(v8h*)(vt + ((size_t)((b * Hc + h) * DHc) + row) * Sc + s0 + c * 8) =
                *(const v8h*)&Ep[row][c * 8];
        }
    }
}

__global__ void rope_kernel(f16* __restrict__ qh, f16* __restrict__ kh,
                            const float* __restrict__ cs, const float* __restrict__ sn)
{
    int i  = blockIdx.x * 256 + threadIdx.x;
    int d2 = i & 63;
    int s  = (i >> 6) & (Sc - 1);
    int bh = i >> 17;
    f16* t = blockIdx.y ? kh : qh;
    float scale = blockIdx.y ? 1.0f : 0.08838834764831845f;
    float c  = cs[s * DHc + 2 * d2];
    float sv = sn[s * DHc + 2 * d2];
    f16* p = t + ((size_t)bh * Sc + s) * DHc + 2 * d2;
    float t0 = (float)p[0], t1 = (float)p[1];
    p[0] = (f16)((t0 * c - t1 * sv) * scale);
    p[1] = (f16)((t1 * c + t0 * sv) * scale);
}

// ---------------------------------------------------------------------------
// Flash attention v9: balanced 8-wave split. 256 blocks (1/CU, XCD-local bh),
// 512 threads. Group 0 (waves 0-3): tile A=15-p, KV 0..16. Group 1 (waves
// 4-7): tile p fully (2p+2 iters, inline epilogue), then tile A's KV tail
// 17..31-2p. Each group runs EXACTLY 17 lockstep iterations for every p ->
// true 2 waves/SIMD the whole time (v8's pairing left group 1 masked ~60%).
// Fixed-max softmax => split partials (o, l) add exactly; combined via LDS.
// Per-group KV staging streams (2 x 64 KB, v6's verified 4-wave pattern).
// ---------------------------------------------------------------------------
__launch_bounds__(512, 2)
__global__ void attn_kernel(const f16* __restrict__ qh, const f16* __restrict__ kh,
                            const f16* __restrict__ vt, float* __restrict__ out)
{
    const int L = blockIdx.x;
    const int slot = L >> 3;
    const int bh = (L & 7) * 4 + (slot >> 3);
    const int p  = slot & 7;
    const int b = bh >> 4, h = bh & 15;
    const int tid = threadIdx.x, lane = tid & 63, w = tid >> 6;
    const int grp = w >> 2, wg = w & 3;
    const int l31 = lane & 31, half = lane >> 5;
    const int sw = l31 & 7;

    // 2 group staging regions (64 KB each); combine buffer unions into smem.
    __shared__ __align__(16) f16 smem[65536];
    f16* gbase = smem + grp * 32768;
    f16* ksm = gbase;             // K dbuf: 2 x 8192 f16
    f16* vsm = gbase + 16384;     // V dbuf: 2 x 8192 f16

    const size_t bhoff = (size_t)bh * Sc * DHc;

    const f16* ksrc[4]; const f16* vsrc[4];
    f16* kdst[4]; f16* vdst[4];
    #pragma unroll
    for (int j = 0; j < 4; ++j) {
        int slot0 = j * 256 + wg * 64;
        {   int r = (slot0 >> 4) + (lane >> 4);
            int c = (lane & 15) ^ (r & 7);
            ksrc[j] = kh + bhoff + (size_t)r * DHc + c * 8;
            kdst[j] = ksm + slot0 * 8; }
        {   int r = (slot0 >> 3) + (lane >> 3);
            int c = (lane & 7) ^ (r & 7);
            vsrc[j] = vt + bhoff + (size_t)r * Sc + c * 8;
            vdst[j] = vsm + slot0 * 8; }
    }

#define STAGE(kt_, buf_) do {                                                   \
        int _ko = (kt_) * 64 * DHc;                                             \
        int _vo = (kt_) * 64;                                                   \
        int _lb = (buf_) * 8192;                                                \
        _Pragma("unroll")                                                       \
        for (int j = 0; j < 4; ++j) {                                           \
            __builtin_amdgcn_global_load_lds(                                   \
                (const __attribute__((address_space(1))) void*)(ksrc[j] + _ko), \
                (__attribute__((address_space(3))) void*)(kdst[j] + _lb), 16, 0, 0); \
            __builtin_amdgcn_global_load_lds(                                   \
                (const __attribute__((address_space(1))) void*)(vsrc[j] + _vo), \
                (__attribute__((address_space(3))) void*)(vdst[j] + _lb), 16, 0, 0); \
        } } while (0)

// epilogue: normalize + softmax over Dh + paired-lane stores (uses o, l_run, qg)
#define EPILOG do {                                                             \
        float inv = 1.f / l_run;                                               \
        float mxd = -1e30f;                                                    \
        _Pragma("unroll")                                                      \
        for (int dt = 0; dt < 4; ++dt)                                         \
            _Pragma("unroll")                                                  \
            for (int r = 0; r < 16; ++r) {                                     \
                o[dt][r] *= inv;                                               \
                mxd = fmaxf(mxd, o[dt][r]);                                    \
            }                                                                  \
        mxd = fmaxf(mxd, __shfl_xor(mxd, 32));                                 \
        float sd = 0.f;                                                        \
        _Pragma("unroll")                                                      \
        for (int dt = 0; dt < 4; ++dt)                                         \
            _Pragma("unroll")                                                  \
            for (int r = 0; r < 16; ++r) {                                     \
                float tv = __expf(o[dt][r] - mxd);                             \
                o[dt][r] = tv;                                                 \
                sd += tv;                                                      \
            }                                                                  \
        sd += __shfl_xor(sd, 32);                                              \
        float rinv = 1.f / sd;                                                 \
        float* orow = out + (size_t)(b * Sc + qg) * Dc + h * DHc;              \
        _Pragma("unroll")                                                      \
        for (int dt = 0; dt < 4; ++dt)                                         \
            _Pragma("unroll")                                                  \
            for (int g2 = 0; g2 < 4; ++g2) {                                   \
                f32x4 vv;                                                      \
                vv[0] = o[dt][4*g2+0] * rinv;                                  \
                vv[1] = o[dt][4*g2+1] * rinv;                                  \
                vv[2] = o[dt][4*g2+2] * rinv;                                  \
                vv[3] = o[dt][4*g2+3] * rinv;                                  \
                *(f32x4*)(orow + dt * 32 + g2 * 8 + half * 4) = vv;            \
            }                                                                  \
    } while (0)

    const int tp_end = 2 * p + 2;            // g1 switch iteration
    const int tailoff = 15 - 2 * p;          // tail kv = i + tailoff

    int qt = grp ? p : (15 - p);
    int q0 = qt * 128 + wg * 32;
    int qg = q0 + l31;

    v8h qf[8];
    {
        const f16* qrow = qh + bhoff + (size_t)qg * DHc;
        #pragma unroll
        for (int s = 0; s < 8; ++s)
            qf[s] = *(const v8h*)(qrow + s * 16 + half * 8);
    }

    float l_run = 0.f;
    v16f o[4];
    #pragma unroll
    for (int i = 0; i < 4; ++i)
        #pragma unroll
        for (int r = 0; r < 16; ++r) o[i][r] = 0.f;

    STAGE(0, 0);                              // kv(0) == 0 for both groups

    #pragma unroll 1
    for (int i = 0; i < 17; ++i) {
        __syncthreads();                      // publishes buf[i&1] (both groups)
        if (i < 16) {
            int inx = i + 1;
            int kn = (grp == 0) ? inx : ((inx < tp_end) ? inx : inx + tailoff);
            STAGE(kn, inx & 1);
        }
        if (grp == 1 && i == tp_end) {
            // tile p finished last iter: epilogue, then switch to tile A tail
            EPILOG;
            l_run = 0.f;
            #pragma unroll
            for (int d2 = 0; d2 < 4; ++d2)
                #pragma unroll
                for (int r = 0; r < 16; ++r) o[d2][r] = 0.f;
            qt = 15 - p; q0 = qt * 128 + wg * 32; qg = q0 + l31;
            const f16* qrow = qh + bhoff + (size_t)qg * DHc;
            #pragma unroll
            for (int s = 0; s < 8; ++s)
                qf[s] = *(const v8h*)(qrow + s * 16 + half * 8);
        }
        const int kv = (grp == 0) ? i : ((i < tp_end) ? i : i + tailoff);
        if (q0 + 31 < kv * 64) continue;      // fully masked; barriers uniform

        const f16* kbuf = ksm + (i & 1) * 8192;
        const f16* vbuf = vsm + (i & 1) * 8192;
        const bool do1 = (kv * 64 + 32 <= q0 + 31);

        v16f st0, st1;
        #pragma unroll
        for (int r = 0; r < 16; ++r) { st0[r] = 0.f; st1[r] = 0.f; }
        #pragma unroll
        for (int s = 0; s < 8; ++s) {
            int c = ((s * 2 + half) ^ sw) * 8;
            v8h kf0 = *(const v8h*)(kbuf + l31 * 128 + c);
            st0 = __builtin_amdgcn_mfma_f32_32x32x16_f16(kf0, qf[s], st0, 0, 0, 0);
            if (do1) {
                v8h kf1 = *(const v8h*)(kbuf + (32 + l31) * 128 + c);
                st1 = __builtin_amdgcn_mfma_f32_32x32x16_f16(kf1, qf[s], st1, 0, 0, 0);
            }
        }

        float sum = 0.f;
        #pragma unroll
        for (int r = 0; r < 16; ++r) {
            int key = kv * 64 + (r & 3) + 8 * (r >> 2) + 4 * half;
            float sv = (key > qg) ? -1e30f : st0[r];
            float pe = __expf(sv);
            st0[r] = pe; sum += pe;
        }
        if (do1) {
            #pragma unroll
            for (int r = 0; r < 16; ++r) {
                int key = kv * 64 + 32 + (r & 3) + 8 * (r >> 2) + 4 * half;
                float sv = (key > qg) ? -1e30f : st1[r];
                float pe = __expf(sv);
                st1[r] = pe; sum += pe;
            }
        }
        sum += __shfl_xor(sum, 32);
        l_run += sum;

        #pragma unroll
        for (int s2 = 0; s2 < 4; ++s2) {
            v4h bfr;
            bfr[0]=(f16)st0[4*s2]; bfr[1]=(f16)st0[4*s2+1];
            bfr[2]=(f16)st0[4*s2+2]; bfr[3]=(f16)st0[4*s2+3];
            int c = ((s2 ^ sw) * 8) + half * 4;
            #pragma unroll
            for (int dt = 0; dt < 4; ++dt) {
                v4h vf = *(const v4h*)(vbuf + (dt * 32 + l31) * 64 + c);
                o[dt] = __builtin_amdgcn_mfma_f32_32x32x8f16(vf, bfr, o[dt], 0, 0, 0);
            }
        }
        if (do1) {
            #pragma unroll
            for (int s2 = 0; s2 < 4; ++s2) {
                v4h bfr;
                bfr[0]=(f16)st1[4*s2]; bfr[1]=(f16)st1[4*s2+1];
                bfr[2]=(f16)st1[4*s2+2]; bfr[3]=(f16)st1[4*s2+3];
                int c = (((4 + s2) ^ sw) * 8) + half * 4;
                #pragma unroll
                for (int dt = 0; dt < 4; ++dt) {
                    v4h vf = *(const v4h*)(vbuf + (dt * 32 + l31) * 64 + c);
                    o[dt] = __builtin_amdgcn_mfma_f32_32x32x8f16(vf, bfr, o[dt], 0, 0, 0);
                }
            }
        }
    }

    // ---- combine: g1's tile-A partial -> g0, then g0 epilogues tile A ----
    __syncthreads();                          // staging reads all retired
    float* ox = (float*)smem;                 // 4 waves x 4096 f32 = 64 KB
    float* lx = (float*)smem + 16384;         // 256 f32
    if (grp == 1) {
        #pragma unroll
        for (int dt = 0; dt < 4; ++dt)
            #pragma unroll
            for (int r = 0; r < 16; ++r)
                ox[wg * 4096 + (dt * 16 + r) * 64 + lane] = o[dt][r];
        lx[wg * 64 + lane] = l_run;
    }
    __syncthreads();
    if (grp == 0) {
        #pragma unroll
        for (int dt = 0; dt < 4; ++dt)
            #pragma unroll
            for (int r = 0; r < 16; ++r)
                o[dt][r] += ox[wg * 4096 + (dt * 16 + r) * 64 + lane];
        l_run += lx[wg * 64 + lane];
        EPILOG;
    }
#undef STAGE
#undef EPILOG
}

extern "C" void kernel_launch(void* const* d_in, const int* in_sizes, int n_in,
                              void* d_out, int out_size, void* d_ws, size_t ws_size,
                              hipStream_t stream)
{
    const float* x  = (const float*)d_in[0];
    const float* wq = (const float*)d_in[1];
    const float* wk = (const float*)d_in[2];
    const float* wv = (const float*)d_in[3];
    const float* cs = (const float*)d_in[4];
    const float* sn = (const float*)d_in[5];
    float* out = (float*)d_out;

    const size_t tsz = (size_t)Bc * Hc * Sc * DHc;   // 8,388,608 halves
    f16* qh = (f16*)d_ws;
    f16* kh = qh + tsz;
    f16* vt = kh + tsz;

    if (ws_size >= 11 * tsz) {
        f16* xh  = vt + tsz;
        f16* wqh = xh + tsz;
        f16* wkh = wqh + tsz / 2;
        f16* wvh = wkh + tsz / 2;
        cvt_kernel<<<20480, 256, 0, stream>>>(x, wq, wk, wv, xh, wqh, wkh, wvh);
        // wqh/wkh/wvh are contiguous -> one stacked-W GEMM, N = 6144
        proj256_kernel<<<768, 512, 0, stream>>>(xh, wqh, cs, sn, qh, kh, vt);
    } else {
        proj_kernel<<<dim3(32, 16, 3), 256, 0, stream>>>(x, wq, wk, wv, qh, kh, vt);
        rope_kernel<<<dim3(16384, 2), 256, 0, stream>>>(qh, kh, cs, sn);
    }
    attn_kernel<<<256, 512, 0, stream>>>(qh, kh, vt, out);
}